// Round 2
// baseline (38043.463 us; speedup 1.0000x reference)
//
#include <hip/hip_runtime.h>

#define TSTEPS 2000
#define NBATCH 16
#define DDIM   512
#define HDIM   512
#define MTOT   (NBATCH * TSTEPS)
#define LEPS   1e-5f

typedef _Float16 f16x8 __attribute__((ext_vector_type(8)));
typedef float    f32x4 __attribute__((ext_vector_type(4)));

// ---------------- Phase 1: w = BN(x @ W^T) ----------------  (unchanged, verified)
__global__ __launch_bounds__(256) void gemm_bn_kernel(
    const float* __restrict__ x, const float* __restrict__ W,
    const float* __restrict__ gamma, const float* __restrict__ beta,
    const float* __restrict__ rmean, const float* __restrict__ rvar,
    float* __restrict__ out_a, float* __restrict__ out_z)
{
  __shared__ float As[64][36];
  __shared__ float Bs[64][36];
  const int tid = threadIdx.x;
  const int m0 = blockIdx.y * 64;
  const int n0 = blockIdx.x * 64;
  const int tx = tid & 15, ty = tid >> 4;
  const int lrow = tid >> 3;
  const int lk = (tid & 7) * 4;
  float acc[4][4];
#pragma unroll
  for (int i = 0; i < 4; ++i)
#pragma unroll
    for (int j = 0; j < 4; ++j) acc[i][j] = 0.f;

  for (int k0 = 0; k0 < DDIM; k0 += 32) {
    float4 x0 = *(const float4*)&x[(size_t)(m0 + lrow) * DDIM + k0 + lk];
    float4 x1 = *(const float4*)&x[(size_t)(m0 + 32 + lrow) * DDIM + k0 + lk];
    float4 w0 = *(const float4*)&W[(size_t)(n0 + lrow) * DDIM + k0 + lk];
    float4 w1 = *(const float4*)&W[(size_t)(n0 + 32 + lrow) * DDIM + k0 + lk];
    __syncthreads();
    *(float4*)&As[lrow][lk]      = x0;
    *(float4*)&As[32 + lrow][lk] = x1;
    *(float4*)&Bs[lrow][lk]      = w0;
    *(float4*)&Bs[32 + lrow][lk] = w1;
    __syncthreads();
#pragma unroll
    for (int kk = 0; kk < 32; kk += 4) {
      float4 av[4], bv[4];
#pragma unroll
      for (int i = 0; i < 4; ++i) av[i] = *(const float4*)&As[ty * 4 + i][kk];
#pragma unroll
      for (int j = 0; j < 4; ++j) bv[j] = *(const float4*)&Bs[tx * 4 + j][kk];
#pragma unroll
      for (int i = 0; i < 4; ++i)
#pragma unroll
        for (int j = 0; j < 4; ++j)
          acc[i][j] += av[i].x * bv[j].x + av[i].y * bv[j].y +
                       av[i].z * bv[j].z + av[i].w * bv[j].w;
    }
  }

  const int gg0 = n0 + tx * 4;
  float4 gm = *(const float4*)&gamma[gg0];
  float4 bt = *(const float4*)&beta[gg0];
  float4 mn = *(const float4*)&rmean[gg0];
  float4 vr = *(const float4*)&rvar[gg0];
  const float inv0 = gm.x * rsqrtf(vr.x + LEPS);
  const float inv1 = gm.y * rsqrtf(vr.y + LEPS);
  const float inv2 = gm.z * rsqrtf(vr.z + LEPS);
  const float inv3 = gm.w * rsqrtf(vr.w + LEPS);
  float* dstb = (gg0 < HDIM) ? out_a : out_z;
  const int col = (gg0 < HDIM) ? gg0 : gg0 - HDIM;
#pragma unroll
  for (int i = 0; i < 4; ++i) {
    const int row = m0 + ty * 4 + i;
    float4 r;
    r.x = (acc[i][0] - mn.x) * inv0 + bt.x;
    r.y = (acc[i][1] - mn.y) * inv1 + bt.y;
    r.z = (acc[i][2] - mn.z) * inv2 + bt.z;
    r.w = (acc[i][3] - mn.w) * inv3 + bt.w;
    *(float4*)&dstb[(size_t)row * HDIM + col] = r;
  }
}

// ---------------- Phase 2: sync-free per-batch MFMA recurrence ----------------
// 16 blocks (1 per batch) x 1024 threads (16 waves). Wave w owns gate columns
// [w*64, w*64+64) = ntiles w*4..w*4+3; waves 0-7 = a-gates, 8-15 = z-gates.
// U held in registers as f16 B-fragments (256 VGPR/thread). Per step:
//   gates(1x1024) = h(1x512) @ U^T via mfma_f32_16x16x32_f16 with a rank-1
//   broadcast A-fragment (all lanes read the same h k-chunk -> every D row
//   equals the true gate row; M-padding costs nothing, reads are broadcasts).
// h state carried in f32 LDS (f16 only at the MFMA input). w_a/w_z prefetched
// 3 steps ahead into an LDS ring (issue early / write late). Two barriers/step,
// no inter-block communication.
__global__ __launch_bounds__(1024) void rnn_mfma_kernel(
    const float* __restrict__ U,
    float* __restrict__ out,              // [16][2000][512]: w_a in, h out (in place)
    const float* __restrict__ wz)         // [16][2000][512]
{
  __shared__ __align__(16) _Float16 hbuf[2][512];  // f16 h for MFMA A
  __shared__ float hf32[2][512];                   // f32 h state
  __shared__ float zbuf[512];
  __shared__ float waring[4][512];
  __shared__ float wzring[4][512];

  const int tid  = threadIdx.x;
  const int w    = tid >> 6;      // wave 0..15
  const int lane = tid & 63;
  const int c    = lane & 15;
  const int hi   = lane >> 4;
  const int b    = blockIdx.x;
  const size_t obase = (size_t)b * TSTEPS * HDIM;

  // ---- persistent U fragments (B-operand), one-time load ----
  // B[k][n] = U[gcol][k]; frag: col = lane&15, k = kt*32 + hi*8 + j (contiguous 8)
  f16x8 ufrag[4][16];
#pragma unroll
  for (int nt = 0; nt < 4; ++nt) {
    const int gcol = w * 64 + nt * 16 + c;
    const float* up = &U[(size_t)gcol * HDIM + hi * 8];
#pragma unroll
    for (int kt = 0; kt < 16; ++kt) {
      float4 lo  = *(const float4*)&up[kt * 32];
      float4 hi4 = *(const float4*)&up[kt * 32 + 4];
      f16x8 f;
      f[0] = (_Float16)lo.x;  f[1] = (_Float16)lo.y;
      f[2] = (_Float16)lo.z;  f[3] = (_Float16)lo.w;
      f[4] = (_Float16)hi4.x; f[5] = (_Float16)hi4.y;
      f[6] = (_Float16)hi4.z; f[7] = (_Float16)hi4.w;
      ufrag[nt][kt] = f;
    }
  }

  // ---- init h = 0 and prefill w ring for t = 0,1,2 ----
  if (tid < 512) {
    hbuf[0][tid] = (_Float16)0.f; hbuf[1][tid] = (_Float16)0.f;
    hf32[0][tid] = 0.f;           hf32[1][tid] = 0.f;
  }
#pragma unroll
  for (int p = 0; p < 3; ++p) {
    if (tid < 512) waring[p][tid]       = out[obase + (size_t)p * HDIM + tid];
    else           wzring[p][tid - 512] = wz [obase + (size_t)p * HDIM + (tid - 512)];
  }
  __syncthreads();

  for (int t = 0; t < TSTEPS; ++t) {
    const int cur  = t & 1;
    const int slot = t & 3;
    const int pf   = t + 3;

    // prefetch w[t+3] early (consumed after barrier; latency hides under MFMA)
    float pfv = 0.f;
    if (pf < TSTEPS) {
      pfv = (tid < 512) ? out[obase + (size_t)pf * HDIM + tid]
                        : wz [obase + (size_t)pf * HDIM + (tid - 512)];
    }

    // ---- MFMA: gates for this wave's 64 columns ----
    f32x4 acc0 = {0.f, 0.f, 0.f, 0.f};
    f32x4 acc1 = {0.f, 0.f, 0.f, 0.f};
    f32x4 acc2 = {0.f, 0.f, 0.f, 0.f};
    f32x4 acc3 = {0.f, 0.f, 0.f, 0.f};
#pragma unroll
    for (int ktg = 0; ktg < 4; ++ktg) {
      f16x8 af[4];
#pragma unroll
      for (int q = 0; q < 4; ++q)
        af[q] = *(const f16x8*)&hbuf[cur][(ktg * 4 + q) * 32 + hi * 8];
#pragma unroll
      for (int q = 0; q < 4; ++q) {
        const int kt = ktg * 4 + q;
        acc0 = __builtin_amdgcn_mfma_f32_16x16x32_f16(af[q], ufrag[0][kt], acc0, 0, 0, 0);
        acc1 = __builtin_amdgcn_mfma_f32_16x16x32_f16(af[q], ufrag[1][kt], acc1, 0, 0, 0);
        acc2 = __builtin_amdgcn_mfma_f32_16x16x32_f16(af[q], ufrag[2][kt], acc2, 0, 0, 0);
        acc3 = __builtin_amdgcn_mfma_f32_16x16x32_f16(af[q], ufrag[3][kt], acc3, 0, 0, 0);
      }
    }
    // lane handles column jloc = lane (= hi*16 + c) of this wave's 64:
    // gate value sits in acc{hi}[any reg] (all D rows equal by construction)
    const float g0 = acc0[0], g1 = acc1[0], g2 = acc2[0], g3 = acc3[0];
    const float gv = (hi == 0) ? g0 : ((hi == 1) ? g1 : ((hi == 2) ? g2 : g3));

    if (w >= 8) {                       // z-waves: publish z-gate pre-activation
      const int j = (w - 8) * 64 + lane;
      zbuf[j] = gv + wzring[slot][j];
    }
    __syncthreads();                    // barrier 1: zbuf ready

    if (w < 8) {                        // a-waves: gate math + h update
      const int j = w * 64 + lane;
      const float a    = gv + waring[slot][j];
      const float zg   = zbuf[j];
      const float z    = 1.f / (1.f + expf(-zg));
      const float hc   = fmaxf(a, 0.f);
      const float hold = hf32[cur][j];
      const float hn   = z * hold + (1.f - z) * hc;
      hf32[cur ^ 1][j] = hn;
      hbuf[cur ^ 1][j] = (_Float16)hn;
      out[obase + (size_t)t * HDIM + j] = hn;
    }
    if (pf < TSTEPS) {                  // late ring write (slot (t+3)&3 != t&3)
      if (tid < 512) waring[pf & 3][tid]       = pfv;
      else           wzring[pf & 3][tid - 512] = pfv;
    }
    __syncthreads();                    // barrier 2: h[t+1] + ring visible
  }
}

extern "C" void kernel_launch(void* const* d_in, const int* in_sizes, int n_in,
                              void* d_out, int out_size, void* d_ws, size_t ws_size,
                              hipStream_t stream) {
  const float* x     = (const float*)d_in[0];
  const float* W     = (const float*)d_in[1];
  const float* U     = (const float*)d_in[2];
  const float* gamma = (const float*)d_in[3];
  const float* beta  = (const float*)d_in[4];
  const float* rmean = (const float*)d_in[5];
  const float* rvar  = (const float*)d_in[6];
  float* out = (float*)d_out;
  float* wzp = (float*)d_ws;            // [16][2000][512] z-half of w

  dim3 g1(HDIM * 2 / 64, MTOT / 64), b1(256);
  gemm_bn_kernel<<<g1, b1, 0, stream>>>(x, W, gamma, beta, rmean, rvar, out, wzp);
  rnn_mfma_kernel<<<dim3(NBATCH), dim3(1024), 0, stream>>>(U, out, wzp);
}

// Round 3
// 3218.200 us; speedup vs baseline: 11.8213x; 11.8213x over previous
//
#include <hip/hip_runtime.h>

#define TSTEPS 2000
#define NBATCH 16
#define DDIM   512
#define HDIM   512
#define MTOT   (NBATCH * TSTEPS)
#define LEPS   1e-5f

typedef _Float16 f16x8 __attribute__((ext_vector_type(8)));
typedef float    f32x4 __attribute__((ext_vector_type(4)));
typedef unsigned long long u64;

// ---------------- Phase 1: w = BN(x @ W^T) ----------------  (unchanged, verified)
__global__ __launch_bounds__(256) void gemm_bn_kernel(
    const float* __restrict__ x, const float* __restrict__ W,
    const float* __restrict__ gamma, const float* __restrict__ beta,
    const float* __restrict__ rmean, const float* __restrict__ rvar,
    float* __restrict__ out_a, float* __restrict__ out_z)
{
  __shared__ float As[64][36];
  __shared__ float Bs[64][36];
  const int tid = threadIdx.x;
  const int m0 = blockIdx.y * 64;
  const int n0 = blockIdx.x * 64;
  const int tx = tid & 15, ty = tid >> 4;
  const int lrow = tid >> 3;
  const int lk = (tid & 7) * 4;
  float acc[4][4];
#pragma unroll
  for (int i = 0; i < 4; ++i)
#pragma unroll
    for (int j = 0; j < 4; ++j) acc[i][j] = 0.f;

  for (int k0 = 0; k0 < DDIM; k0 += 32) {
    float4 x0 = *(const float4*)&x[(size_t)(m0 + lrow) * DDIM + k0 + lk];
    float4 x1 = *(const float4*)&x[(size_t)(m0 + 32 + lrow) * DDIM + k0 + lk];
    float4 w0 = *(const float4*)&W[(size_t)(n0 + lrow) * DDIM + k0 + lk];
    float4 w1 = *(const float4*)&W[(size_t)(n0 + 32 + lrow) * DDIM + k0 + lk];
    __syncthreads();
    *(float4*)&As[lrow][lk]      = x0;
    *(float4*)&As[32 + lrow][lk] = x1;
    *(float4*)&Bs[lrow][lk]      = w0;
    *(float4*)&Bs[32 + lrow][lk] = w1;
    __syncthreads();
#pragma unroll
    for (int kk = 0; kk < 32; kk += 4) {
      float4 av[4], bv[4];
#pragma unroll
      for (int i = 0; i < 4; ++i) av[i] = *(const float4*)&As[ty * 4 + i][kk];
#pragma unroll
      for (int j = 0; j < 4; ++j) bv[j] = *(const float4*)&Bs[tx * 4 + j][kk];
#pragma unroll
      for (int i = 0; i < 4; ++i)
#pragma unroll
        for (int j = 0; j < 4; ++j)
          acc[i][j] += av[i].x * bv[j].x + av[i].y * bv[j].y +
                       av[i].z * bv[j].z + av[i].w * bv[j].w;
    }
  }

  const int gg0 = n0 + tx * 4;
  float4 gm = *(const float4*)&gamma[gg0];
  float4 bt = *(const float4*)&beta[gg0];
  float4 mn = *(const float4*)&rmean[gg0];
  float4 vr = *(const float4*)&rvar[gg0];
  const float inv0 = gm.x * rsqrtf(vr.x + LEPS);
  const float inv1 = gm.y * rsqrtf(vr.y + LEPS);
  const float inv2 = gm.z * rsqrtf(vr.z + LEPS);
  const float inv3 = gm.w * rsqrtf(vr.w + LEPS);
  float* dstb = (gg0 < HDIM) ? out_a : out_z;
  const int col = (gg0 < HDIM) ? gg0 : gg0 - HDIM;
#pragma unroll
  for (int i = 0; i < 4; ++i) {
    const int row = m0 + ty * 4 + i;
    float4 r;
    r.x = (acc[i][0] - mn.x) * inv0 + bt.x;
    r.y = (acc[i][1] - mn.y) * inv1 + bt.y;
    r.z = (acc[i][2] - mn.z) * inv2 + bt.z;
    r.w = (acc[i][3] - mn.w) * inv3 + bt.w;
    *(float4*)&dstb[(size_t)row * HDIM + col] = r;
  }
}

// ---------------- Phase 2: 8-blocks/batch, fence-free tagged exchange ----------
// 128 blocks = 16 batches x 8 groups; bid = g*16 + b keeps a batch's 8 blocks on
// one XCD (bid % 8 == b % 8; perf hint only, correctness is agent-scope atomics).
// Block (b,g) owns h cols [g*64, g*64+64): U rows {g*64..+64} (a) and
// {512+g*64..+64} (z) as f16 MFMA B-fragments, 64 VGPR/thread (16 x f16x8).
// Per step: gates via broadcast-A mfma_f32_16x16x32_f16; 64 updater threads
// compute h_new and publish {tag=t+1, f32 h} packed in ONE 8-byte relaxed
// agent-scope atomic per element (no flags, no fences). Readers equality-spin
// on the tag. Parity double-buffer makes overwrites race-free:
// publish(t+1) happens after barriers proving all our reads of slot tag t-1
// are complete, and a peer can only publish t+2 after seeing OUR t+1.
__global__ __launch_bounds__(512, 2) void rnn_sync_kernel(
    const float* __restrict__ U,
    float* __restrict__ out,              // [16][2000][512]: w_a in, h out (in place)
    const float* __restrict__ wz,         // [16][2000][512]
    u64* __restrict__ xbuf)               // [2][16][512] {tag,val} -- memset 0 per launch
{
  __shared__ __align__(16) _Float16 hbuf[512];   // f16 h for MFMA A (full h)
  __shared__ float hf32[512];                    // f32 h state (full h)
  __shared__ float gbuf[128];                    // this block's 128 gate values
  __shared__ float waring[4][64];
  __shared__ float wzring[4][64];

  const int tid  = threadIdx.x;
  const int w    = tid >> 6;       // wave 0..7
  const int lane = tid & 63;
  const int c    = lane & 15;
  const int hi   = lane >> 4;
  const int bid  = blockIdx.x;
  const int b    = bid & 15, g = bid >> 4;
  const int g0   = g * 64;
  const size_t obase = (size_t)b * TSTEPS * HDIM;

  // ---- persistent U B-fragments: wave w owns local gate cols [w*16, w*16+16) ----
  // local col L: L<64 -> a-gate row g0+L ; L>=64 -> z-gate row 512+g0+(L-64)
  const int L    = w * 16 + c;
  const int urow = (L < 64) ? (g0 + L) : (HDIM + g0 + (L - 64));
  f16x8 ufrag[16];
  {
    const float* up = &U[(size_t)urow * HDIM + hi * 8];
#pragma unroll
    for (int kt = 0; kt < 16; ++kt) {
      float4 lo = *(const float4*)&up[kt * 32];
      float4 h4 = *(const float4*)&up[kt * 32 + 4];
      f16x8 f;
      f[0] = (_Float16)lo.x; f[1] = (_Float16)lo.y;
      f[2] = (_Float16)lo.z; f[3] = (_Float16)lo.w;
      f[4] = (_Float16)h4.x; f[5] = (_Float16)h4.y;
      f[6] = (_Float16)h4.z; f[7] = (_Float16)h4.w;
      ufrag[kt] = f;
    }
  }

  hbuf[tid] = (_Float16)0.f;
  hf32[tid] = 0.f;
#pragma unroll
  for (int p = 0; p < 3; ++p) {
    if (tid < 64)        waring[p][tid]      = out[obase + (size_t)p * HDIM + g0 + tid];
    else if (tid < 128)  wzring[p][tid - 64] = wz [obase + (size_t)p * HDIM + g0 + (tid - 64)];
  }
  __syncthreads();

  for (int t = 0; t < TSTEPS; ++t) {
    // ---- A: acquire h_t (t=0: zeros already in LDS) ----
    if (t > 0) {
      u64* xb = &xbuf[((size_t)(t & 1) * NBATCH + b) * HDIM];
      u64 v;
      do {
        v = __hip_atomic_load(&xb[tid], __ATOMIC_RELAXED, __HIP_MEMORY_SCOPE_AGENT);
      } while ((unsigned)(v >> 32) != (unsigned)t);
      const float hv = __uint_as_float((unsigned)v);
      hbuf[tid] = (_Float16)hv;
      hf32[tid] = hv;
    }
    // early-issue prefetch of w[t+3] (written to ring after bar2)
    const int pf = t + 3;
    float pv = 0.f;
    if (pf < TSTEPS) {
      if (tid < 64)       pv = out[obase + (size_t)pf * HDIM + g0 + tid];
      else if (tid < 128) pv = wz [obase + (size_t)pf * HDIM + g0 + (tid - 64)];
    }
    __syncthreads();                                   // bar1: hbuf/hf32 ready

    const float hold = (tid < 64) ? hf32[g0 + tid] : 0.f;  // read before bar2

    // ---- B: gates for this wave's 16 cols (broadcast-A MFMA, split-k chains) ----
    f32x4 acc0 = {0.f, 0.f, 0.f, 0.f};
    f32x4 acc1 = {0.f, 0.f, 0.f, 0.f};
#pragma unroll
    for (int ktg = 0; ktg < 4; ++ktg) {
      f16x8 af[4];
#pragma unroll
      for (int q = 0; q < 4; ++q)
        af[q] = *(const f16x8*)&hbuf[ktg * 128 + q * 32 + hi * 8];
      acc0 = __builtin_amdgcn_mfma_f32_16x16x32_f16(af[0], ufrag[ktg * 4 + 0], acc0, 0, 0, 0);
      acc1 = __builtin_amdgcn_mfma_f32_16x16x32_f16(af[1], ufrag[ktg * 4 + 1], acc1, 0, 0, 0);
      acc0 = __builtin_amdgcn_mfma_f32_16x16x32_f16(af[2], ufrag[ktg * 4 + 2], acc0, 0, 0, 0);
      acc1 = __builtin_amdgcn_mfma_f32_16x16x32_f16(af[3], ufrag[ktg * 4 + 3], acc1, 0, 0, 0);
    }
    if (lane < 16) gbuf[w * 16 + lane] = acc0[0] + acc1[0];  // hi==0 lanes, col=c
    __syncthreads();                                   // bar2: gbuf ready

    // ---- C: h update + tagged publish (threads 0..63) ----
    if (tid < 64) {
      const float a  = gbuf[tid]      + waring[t & 3][tid];
      const float zg = gbuf[64 + tid] + wzring[t & 3][tid];
      const float z  = 1.f / (1.f + expf(-zg));
      const float hc = fmaxf(a, 0.f);
      const float hn = z * hold + (1.f - z) * hc;
      out[obase + (size_t)t * HDIM + g0 + tid] = hn;
      if (t + 1 < TSTEPS) {
        const u64 pkt = ((u64)(unsigned)(t + 1) << 32) | (u64)__float_as_uint(hn);
        __hip_atomic_store(&xbuf[((size_t)((t + 1) & 1) * NBATCH + b) * HDIM + g0 + tid],
                           pkt, __ATOMIC_RELAXED, __HIP_MEMORY_SCOPE_AGENT);
      }
    }
    if (pf < TSTEPS) {                                 // late ring write (slot != t&3)
      if (tid < 64)       waring[pf & 3][tid]      = pv;
      else if (tid < 128) wzring[pf & 3][tid - 64] = pv;
    }
    // no bar3 needed: all step-t reads of hbuf/hf32 happen before bar2; gbuf is
    // rewritten only after next iteration's bar1; spin handles xbuf visibility.
  }
}

extern "C" void kernel_launch(void* const* d_in, const int* in_sizes, int n_in,
                              void* d_out, int out_size, void* d_ws, size_t ws_size,
                              hipStream_t stream) {
  const float* x     = (const float*)d_in[0];
  const float* W     = (const float*)d_in[1];
  const float* U     = (const float*)d_in[2];
  const float* gamma = (const float*)d_in[3];
  const float* beta  = (const float*)d_in[4];
  const float* rmean = (const float*)d_in[5];
  const float* rvar  = (const float*)d_in[6];
  float* out = (float*)d_out;

  const size_t wz_bytes = (size_t)MTOT * HDIM * sizeof(float);   // 65,536,000
  float* wzp = (float*)d_ws;
  u64*  xbuf = (u64*)((char*)d_ws + wz_bytes);                   // [2][16][512] u64

  // reset tags every launch (captured in graph -> runs every replay)
  hipMemsetAsync(xbuf, 0, (size_t)2 * NBATCH * HDIM * sizeof(u64), stream);

  dim3 g1(HDIM * 2 / 64, MTOT / 64), b1(256);
  gemm_bn_kernel<<<g1, b1, 0, stream>>>(x, W, gamma, beta, rmean, rvar, out, wzp);
  rnn_sync_kernel<<<dim3(128), dim3(512), 0, stream>>>(U, out, wzp, xbuf);
}

// Round 4
// 2662.824 us; speedup vs baseline: 14.2869x; 1.2086x over previous
//
#include <hip/hip_runtime.h>

#define TSTEPS 2000
#define NBATCH 16
#define DDIM   512
#define HDIM   512
#define MTOT   (NBATCH * TSTEPS)
#define LEPS   1e-5f

typedef _Float16 f16x8 __attribute__((ext_vector_type(8)));
typedef _Float16 f16x4 __attribute__((ext_vector_type(4)));
typedef float    f32x4 __attribute__((ext_vector_type(4)));
typedef unsigned long long u64;

// ---------------- Phase 1: w = BN(x @ W^T), f16 MFMA ----------------
// C[32000,1024] = x[32000,512] @ W[1024,512]^T. 128x128 tile, BK=64, 256 thr
// (4 waves; wave w owns n-cols [w*32,(w+1)*32)). Reg-staged f32->f16 with
// T2 XOR-swizzle (byte ^= (row&7)<<4) on both ds_write and ds_read.
// BN fused in epilogue; a-half (col<512) -> out_a, z-half -> out_z.
__global__ __launch_bounds__(256) void gemm_bn_f16_kernel(
    const float* __restrict__ x, const float* __restrict__ W,
    const float* __restrict__ gamma, const float* __restrict__ beta,
    const float* __restrict__ rmean, const float* __restrict__ rvar,
    float* __restrict__ out_a, float* __restrict__ out_z)
{
  __shared__ _Float16 Asm[128 * 64];
  __shared__ _Float16 Bsm[128 * 64];
  const int tid  = threadIdx.x;
  const int wv   = tid >> 6;
  const int lane = tid & 63;
  const int c    = lane & 15;
  const int hi   = lane >> 4;
  const int m0   = blockIdx.x * 128;
  const int n0   = blockIdx.y * 128;

  // per-column BN params (col = n0 + wv*32 + nt*16 + c)
  float invg[2], mng[2], btg[2];
#pragma unroll
  for (int nt = 0; nt < 2; ++nt) {
    const int gc = n0 + wv * 32 + nt * 16 + c;
    invg[nt] = gamma[gc] * rsqrtf(rvar[gc] + LEPS);
    mng[nt]  = rmean[gc];
    btg[nt]  = beta[gc];
  }

  f32x4 acc[8][2];
#pragma unroll
  for (int mt = 0; mt < 8; ++mt)
#pragma unroll
    for (int nt = 0; nt < 2; ++nt) acc[mt][nt] = (f32x4){0.f, 0.f, 0.f, 0.f};

  const int sf4  = tid & 15;   // float4 slot within 64-f32 row
  const int srow = tid >> 4;   // 16 rows per pass, 8 passes

  for (int k0 = 0; k0 < DDIM; k0 += 64) {
    __syncthreads();                       // previous iter's LDS reads done
#pragma unroll
    for (int p = 0; p < 8; ++p) {
      const int r = p * 16 + srow;
      float4 va = *(const float4*)&x[(size_t)(m0 + r) * DDIM + k0 + sf4 * 4];
      float4 vb = *(const float4*)&W[(size_t)(n0 + r) * DDIM + k0 + sf4 * 4];
      f16x4 ha, hb;
      ha[0] = (_Float16)va.x; ha[1] = (_Float16)va.y;
      ha[2] = (_Float16)va.z; ha[3] = (_Float16)va.w;
      hb[0] = (_Float16)vb.x; hb[1] = (_Float16)vb.y;
      hb[2] = (_Float16)vb.z; hb[3] = (_Float16)vb.w;
      const int byo = r * 128 + ((sf4 * 8) ^ ((r & 7) << 4));
      *(f16x4*)((char*)Asm + byo) = ha;
      *(f16x4*)((char*)Bsm + byo) = hb;
    }
    __syncthreads();                       // stage visible
#pragma unroll
    for (int kc = 0; kc < 2; ++kc) {
      const int kof = (kc * 32 + hi * 8) * 2;    // byte offset of k-chunk
      f16x8 bfr[2];
#pragma unroll
      for (int nt = 0; nt < 2; ++nt) {
        const int rr = wv * 32 + nt * 16 + c;
        bfr[nt] = *(const f16x8*)((const char*)Bsm + rr * 128 + (kof ^ ((rr & 7) << 4)));
      }
#pragma unroll
      for (int mt = 0; mt < 8; ++mt) {
        const int rr = mt * 16 + c;
        f16x8 afr = *(const f16x8*)((const char*)Asm + rr * 128 + (kof ^ ((rr & 7) << 4)));
        acc[mt][0] = __builtin_amdgcn_mfma_f32_16x16x32_f16(afr, bfr[0], acc[mt][0], 0, 0, 0);
        acc[mt][1] = __builtin_amdgcn_mfma_f32_16x16x32_f16(afr, bfr[1], acc[mt][1], 0, 0, 0);
      }
    }
  }

  // epilogue: BN + split store. D: col = lane&15, row = hi*4 + reg.
  const bool isA = (n0 < HDIM);
  float* dst = isA ? out_a : out_z;
  const int cb = isA ? n0 : (n0 - HDIM);
#pragma unroll
  for (int mt = 0; mt < 8; ++mt)
#pragma unroll
    for (int nt = 0; nt < 2; ++nt) {
      const int col = cb + wv * 32 + nt * 16 + c;
#pragma unroll
      for (int i = 0; i < 4; ++i) {
        const int row = m0 + mt * 16 + hi * 4 + i;
        dst[(size_t)row * HDIM + col] = (acc[mt][nt][i] - mng[nt]) * invg[nt] + btg[nt];
      }
    }
}

// ---------------- Phase 2: 8-blocks/batch, fence-free tagged exchange ----------
// Same structure as round 3 (verified). Changes: (1) w-prefetch pipelined a FULL
// iteration ahead (ring depth 8, pv_carry register; ring write at top-of-loop
// where only >1-iteration-old loads are outstanding -> no vmcnt stall on the
// critical path); (2) 4 independent MFMA chains (depth 4, was 2x8); (3) publish
// store issued before the out store; (4) __expf.
__global__ __launch_bounds__(512, 2) void rnn_sync_kernel(
    const float* __restrict__ U,
    float* __restrict__ out,              // [16][2000][512]: w_a in, h out (in place)
    const float* __restrict__ wz,         // [16][2000][512]
    u64* __restrict__ xbuf)               // [2][16][512] {tag,val} -- memset 0 per launch
{
  __shared__ __align__(16) _Float16 hbuf[512];
  __shared__ float hf32[512];
  __shared__ float gbuf[128];
  __shared__ float waring[8][64];
  __shared__ float wzring[8][64];

  const int tid  = threadIdx.x;
  const int w    = tid >> 6;
  const int lane = tid & 63;
  const int c    = lane & 15;
  const int hi   = lane >> 4;
  const int bid  = blockIdx.x;
  const int b    = bid & 15, g = bid >> 4;
  const int g0   = g * 64;
  const size_t obase = (size_t)b * TSTEPS * HDIM;

  // persistent U B-fragments: wave w owns local gate cols [w*16, w*16+16)
  const int L    = w * 16 + c;
  const int urow = (L < 64) ? (g0 + L) : (HDIM + g0 + (L - 64));
  f16x8 ufrag[16];
  {
    const float* up = &U[(size_t)urow * HDIM + hi * 8];
#pragma unroll
    for (int kt = 0; kt < 16; ++kt) {
      float4 lo = *(const float4*)&up[kt * 32];
      float4 h4 = *(const float4*)&up[kt * 32 + 4];
      f16x8 f;
      f[0] = (_Float16)lo.x; f[1] = (_Float16)lo.y;
      f[2] = (_Float16)lo.z; f[3] = (_Float16)lo.w;
      f[4] = (_Float16)h4.x; f[5] = (_Float16)h4.y;
      f[6] = (_Float16)h4.z; f[7] = (_Float16)h4.w;
      ufrag[kt] = f;
    }
  }

  hbuf[tid] = (_Float16)0.f;
  hf32[tid] = 0.f;
#pragma unroll
  for (int p = 0; p < 4; ++p) {
    if (tid < 64)        waring[p][tid]      = out[obase + (size_t)p * HDIM + g0 + tid];
    else if (tid < 128)  wzring[p][tid - 64] = wz [obase + (size_t)p * HDIM + g0 + (tid - 64)];
  }
  float pv_carry = 0.f;                      // holds w[4] entering the loop
  if (tid < 64)       pv_carry = out[obase + (size_t)4 * HDIM + g0 + tid];
  else if (tid < 128) pv_carry = wz [obase + (size_t)4 * HDIM + g0 + (tid - 64)];
  __syncthreads();

  for (int t = 0; t < TSTEPS; ++t) {
    // ---- A: acquire h_t (t=0: zeros already in LDS) ----
    if (t > 0) {
      u64* xb = &xbuf[((size_t)(t & 1) * NBATCH + b) * HDIM];
      u64 v;
      do {
        v = __hip_atomic_load(&xb[tid], __ATOMIC_RELAXED, __HIP_MEMORY_SCOPE_AGENT);
      } while ((unsigned)(v >> 32) != (unsigned)t);
      const float hv = __uint_as_float((unsigned)v);
      hbuf[tid] = (_Float16)hv;
      hf32[tid] = hv;
    }
    // ring write for step t+4: pv_carry was ISSUED last iteration (~1 full step
    // ago), so the vmcnt wait here is free. Slot (t+4)&7 is untouched by any
    // reader of steps t..t+3 (distinct mod 8) and step t-4's read is behind
    // two barriers.
    if (t + 4 < TSTEPS) {
      if (tid < 64)       waring[(t + 4) & 7][tid]      = pv_carry;
      else if (tid < 128) wzring[(t + 4) & 7][tid - 64] = pv_carry;
    }
    // issue next prefetch (w[t+5]); consumed next iteration
    if (t + 5 < TSTEPS) {
      if (tid < 64)       pv_carry = out[obase + (size_t)(t + 5) * HDIM + g0 + tid];
      else if (tid < 128) pv_carry = wz [obase + (size_t)(t + 5) * HDIM + g0 + (tid - 64)];
    }
    __syncthreads();                                   // bar1: hbuf/hf32/ring ready

    const float hold = (tid < 64) ? hf32[g0 + tid] : 0.f;  // read before bar2

    // ---- B: gates, 4 independent MFMA chains (depth 4) ----
    f32x4 acc0 = {0.f, 0.f, 0.f, 0.f};
    f32x4 acc1 = {0.f, 0.f, 0.f, 0.f};
    f32x4 acc2 = {0.f, 0.f, 0.f, 0.f};
    f32x4 acc3 = {0.f, 0.f, 0.f, 0.f};
#pragma unroll
    for (int ktg = 0; ktg < 4; ++ktg) {
      f16x8 af[4];
#pragma unroll
      for (int q = 0; q < 4; ++q)
        af[q] = *(const f16x8*)&hbuf[ktg * 128 + q * 32 + hi * 8];
      acc0 = __builtin_amdgcn_mfma_f32_16x16x32_f16(af[0], ufrag[ktg * 4 + 0], acc0, 0, 0, 0);
      acc1 = __builtin_amdgcn_mfma_f32_16x16x32_f16(af[1], ufrag[ktg * 4 + 1], acc1, 0, 0, 0);
      acc2 = __builtin_amdgcn_mfma_f32_16x16x32_f16(af[2], ufrag[ktg * 4 + 2], acc2, 0, 0, 0);
      acc3 = __builtin_amdgcn_mfma_f32_16x16x32_f16(af[3], ufrag[ktg * 4 + 3], acc3, 0, 0, 0);
    }
    if (lane < 16) gbuf[w * 16 + lane] = (acc0[0] + acc1[0]) + (acc2[0] + acc3[0]);
    __syncthreads();                                   // bar2: gbuf ready

    // ---- C: h update + tagged publish (threads 0..63) ----
    if (tid < 64) {
      const float a  = gbuf[tid]      + waring[t & 7][tid];
      const float zg = gbuf[64 + tid] + wzring[t & 7][tid];
      const float z  = 1.f / (1.f + __expf(-zg));
      const float hc = fmaxf(a, 0.f);
      const float hn = z * hold + (1.f - z) * hc;
      if (t + 1 < TSTEPS) {                            // publish FIRST (critical path)
        const u64 pkt = ((u64)(unsigned)(t + 1) << 32) | (u64)__float_as_uint(hn);
        __hip_atomic_store(&xbuf[((size_t)((t + 1) & 1) * NBATCH + b) * HDIM + g0 + tid],
                           pkt, __ATOMIC_RELAXED, __HIP_MEMORY_SCOPE_AGENT);
      }
      out[obase + (size_t)t * HDIM + g0 + tid] = hn;   // off critical path
    }
  }
}

extern "C" void kernel_launch(void* const* d_in, const int* in_sizes, int n_in,
                              void* d_out, int out_size, void* d_ws, size_t ws_size,
                              hipStream_t stream) {
  const float* x     = (const float*)d_in[0];
  const float* W     = (const float*)d_in[1];
  const float* U     = (const float*)d_in[2];
  const float* gamma = (const float*)d_in[3];
  const float* beta  = (const float*)d_in[4];
  const float* rmean = (const float*)d_in[5];
  const float* rvar  = (const float*)d_in[6];
  float* out = (float*)d_out;

  const size_t wz_bytes = (size_t)MTOT * HDIM * sizeof(float);   // 65,536,000
  float* wzp = (float*)d_ws;
  u64*  xbuf = (u64*)((char*)d_ws + wz_bytes);                   // [2][16][512] u64

  hipMemsetAsync(xbuf, 0, (size_t)2 * NBATCH * HDIM * sizeof(u64), stream);

  dim3 g1(MTOT / 128, (HDIM * 2) / 128), b1(256);
  gemm_bn_f16_kernel<<<g1, b1, 0, stream>>>(x, W, gamma, beta, rmean, rvar, out, wzp);
  rnn_sync_kernel<<<dim3(128), dim3(512), 0, stream>>>(U, out, wzp, xbuf);
}